// Round 24
// baseline (244.772 us; speedup 1.0000x reference)
//
#include <hip/hip_runtime.h>
#include <hip/hip_bf16.h>

#define NN 20000
#define EF 640000
#define EG 160000
#define CAP 128   // per-node edge bucket capacity (deg ~ Poisson(32))

typedef __attribute__((ext_vector_type(8))) short bf16x8;
typedef __attribute__((ext_vector_type(4))) float f32x4;
typedef __attribute__((ext_vector_type(2))) float f32x2;

__device__ inline short f2bf(float f) {
    union { float f; unsigned u; } x; x.f = f;
    unsigned r = x.u + 0x7FFF + ((x.u >> 16) & 1);   // RNE
    return (short)(r >> 16);
}
__device__ inline float bf2f(short s) {
    union { float f; unsigned u; } x;
    x.u = ((unsigned)(unsigned short)s) << 16;
    return x.f;
}
__device__ inline float blo(unsigned u) {
    union { float f; unsigned u; } c; c.u = u << 16; return c.f;
}
__device__ inline float bhi(unsigned u) {
    union { float f; unsigned u; } c; c.u = u & 0xFFFF0000u; return c.f;
}
__device__ inline unsigned pk2(float a, float b) {
    return (unsigned)(unsigned short)f2bf(a) | ((unsigned)(unsigned short)f2bf(b) << 16);
}
__device__ inline float clip5(float v) { return fminf(fmaxf(v, -5.f), 5.f); }

// ---------------------------------------------------------------------------
// prep_kernel: fused {init cnt/inv} + {5x weight->frag-major} + WpeF + Wcomb
// ---------------------------------------------------------------------------
__global__ __launch_bounds__(256) void prep_kernel(
    int* __restrict__ cnt, int* __restrict__ inv,
    const float* __restrict__ W0, const float* __restrict__ W1,
    const float* __restrict__ W2, const float* __restrict__ W3,
    const float* __restrict__ W4, short* __restrict__ B0,
    short* __restrict__ B1, short* __restrict__ B2,
    short* __restrict__ B3, short* __restrict__ B4,
    const float* __restrict__ Wpe, short* __restrict__ WpeF,
    const float* __restrict__ Wap, const float* __restrict__ bap,
    const float* __restrict__ Woute, const float* __restrict__ boute,
    short* __restrict__ WcombF, float* __restrict__ bcomb)
{
    int b = blockIdx.x;
    int tid = threadIdx.x;
    if (b < 2500) {
        int i = b * 256 + tid;
        if (i < NN) cnt[i] = 0;
        if (i < EF) inv[i] = -1;
    } else if (b < 2540) {
        int u = b - 2500;
        int mat = u >> 3, blk = u & 7;
        const float* W; short* B;
        switch (mat) {
            case 0: W = W0; B = B0; break;
            case 1: W = W1; B = B1; break;
            case 2: W = W2; B = B2; break;
            case 3: W = W3; B = B3; break;
            default: W = W4; B = B4; break;
        }
        int i = blk * 256 + tid;
        int f = i >> 6, lane = i & 63;
        int n = f >> 2, ks = f & 3;
        int col = n * 16 + (lane & 15);
        int k0 = ks * 32 + (lane >> 4) * 8;
        #pragma unroll
        for (int j = 0; j < 8; ++j)
            B[(size_t)i * 8 + j] = f2bf(W[(size_t)(k0 + j) * 128 + col]);
    } else if (b == 2540) {
        int i = tid;
        int lane = i & 63;
        int ks = i >> 6;
        int l15 = lane & 15, lhi = lane >> 4;
        #pragma unroll
        for (int j = 0; j < 8; ++j) {
            int k = ks * 32 + lhi * 8 + j;
            WpeF[(size_t)i * 8 + j] = (l15 < 8) ? f2bf(Wpe[k * 8 + l15]) : 0;
        }
    } else {
        int j = tid;
        if (j < 128) {
            #pragma unroll
            for (int t = 0; t < 32; ++t) WcombF[j * 32 + t] = 0;
        }
        __syncthreads();
        if (j < 128) {
            float bc = boute[j];
            for (int k = 0; k < 128; ++k) bc += bap[k] * Woute[k * 128 + j];
            bcomb[j] = bc;
            int n = j >> 4, l15 = j & 15;
            #pragma unroll
            for (int i = 0; i < 8; ++i) {
                float s = 0.f;
                for (int k = 0; k < 128; ++k) s += Wap[i * 128 + k] * Woute[k * 128 + j];
                WcombF[((size_t)n * 64 + l15) * 8 + i] = f2bf(s);
            }
        }
    }
}

// ---------------------------------------------------------------------------
// L2: inv [0,625) || qkv_fused [625,881)
// ---------------------------------------------------------------------------
__global__ __launch_bounds__(256, 2) void iq_kernel(
    const int* __restrict__ emap, int* __restrict__ inv,
    const float* __restrict__ h,
    const short* __restrict__ WqF, const short* __restrict__ WkF,
    const short* __restrict__ WvF,
    const float* __restrict__ bq, const float* __restrict__ bk,
    const float* __restrict__ bv,
    short* __restrict__ Qb, short* __restrict__ Kb,
    unsigned char* __restrict__ K8, unsigned char* __restrict__ V8)
{
    if (blockIdx.x < 625) {
        int i = blockIdx.x * 256 + threadIdx.x;
        if (i < EG) inv[emap[i]] = i;
        return;
    }
    int bq0 = blockIdx.x - 625;   // 0..255
    int lane = threadIdx.x & 63;
    int w = threadIdx.x >> 6;
    int l15 = lane & 15, lhi = lane >> 4;

    #pragma unroll
    for (int sel = 0; sel < 3; ++sel) {
        const short* BF  = sel == 0 ? WqF : sel == 1 ? WkF : WvF;
        const float* bias = sel == 0 ? bq : sel == 1 ? bk : bv;
        bf16x8 bf[8][4];
        #pragma unroll
        for (int n = 0; n < 8; ++n)
            #pragma unroll
            for (int ks = 0; ks < 4; ++ks)
                bf[n][ks] = *(const bf16x8*)(BF + ((size_t)((n * 4 + ks) * 64 + lane)) * 8);

        for (int t = bq0; t < 313; t += 256) {
            int r = t * 64 + w * 16 + l15;
            bool ok = r < NN;
            bf16x8 a[4];
            #pragma unroll
            for (int ks = 0; ks < 4; ++ks) {
                if (ok) {
                    const float* ap = h + (size_t)r * 128 + ks * 32 + lhi * 8;
                    float4 f0 = *(const float4*)ap;
                    float4 f1 = *(const float4*)(ap + 4);
                    a[ks][0] = f2bf(f0.x); a[ks][1] = f2bf(f0.y);
                    a[ks][2] = f2bf(f0.z); a[ks][3] = f2bf(f0.w);
                    a[ks][4] = f2bf(f1.x); a[ks][5] = f2bf(f1.y);
                    a[ks][6] = f2bf(f1.z); a[ks][7] = f2bf(f1.w);
                } else {
                    #pragma unroll
                    for (int j = 0; j < 8; ++j) a[ks][j] = 0;
                }
            }
            #pragma unroll
            for (int n = 0; n < 8; ++n) {
                f32x4 acc = (f32x4){0.f, 0.f, 0.f, 0.f};
                #pragma unroll
                for (int ks = 0; ks < 4; ++ks)
                    acc = __builtin_amdgcn_mfma_f32_16x16x32_bf16(bf[n][ks], a[ks], acc, 0, 0, 0);
                if (!ok) continue;
                int col0 = n * 16 + lhi * 4;
                float4 bs = *(const float4*)(bias + col0);
                float g0 = acc[0] + bs.x, g1 = acc[1] + bs.y;
                float g2 = acc[2] + bs.z, g3 = acc[3] + bs.w;
                if (sel == 0) {
                    *(uint2*)(Qb + (size_t)r * 128 + col0) =
                        make_uint2(pk2(g0, g1), pk2(g2, g3));
                } else if (sel == 1) {
                    *(uint2*)(Kb + (size_t)r * 128 + col0) =
                        make_uint2(pk2(g0, g1), pk2(g2, g3));
                    int w8 = __builtin_amdgcn_cvt_pk_fp8_f32(g0, g1, 0, false);
                    w8 = __builtin_amdgcn_cvt_pk_fp8_f32(g2, g3, w8, true);
                    *(unsigned*)(K8 + (size_t)r * 128 + col0) = (unsigned)w8;
                } else {
                    int w8 = __builtin_amdgcn_cvt_pk_fp8_f32(g0, g1, 0, false);
                    w8 = __builtin_amdgcn_cvt_pk_fp8_f32(g2, g3, w8, true);
                    *(unsigned*)(V8 + (size_t)r * 128 + col0) = (unsigned)w8;
                }
            }
        }
    }
}

// ---------------------------------------------------------------------------
// L3: score_g [0,5000) || bucket-scatter [5000,7500)
// ---------------------------------------------------------------------------
__global__ __launch_bounds__(256) void ss_kernel(
    const short* __restrict__ Qb, const short* __restrict__ Kb,
    const int* __restrict__ src, const int* __restrict__ dst,
    const float* __restrict__ adj2, const float* __restrict__ rel,
    const int* __restrict__ emap,
    short* __restrict__ gsb, float* __restrict__ s1f,
    const int* __restrict__ inv, int* __restrict__ cnt,
    uint2* __restrict__ em)
{
    if (blockIdx.x < 5000) {
        int tid = blockIdx.x * 256 + threadIdx.x;
        if (tid >= EG * 8) return;
        int i = tid >> 3, hh = tid & 7;
        int e = emap[i];
        int s = src[e], d = dst[e];
        const bf16x8* Kp = (const bf16x8*)(Kb + (size_t)s * 128 + hh * 16);
        const bf16x8* Qp = (const bf16x8*)(Qb + (size_t)d * 128 + hh * 16);
        bf16x8 k0 = Kp[0], k1 = Kp[1];
        bf16x8 q0 = Qp[0], q1 = Qp[1];
        float dot = 0.f;
        #pragma unroll
        for (int j = 0; j < 8; ++j) dot += bf2f(k0[j]) * bf2f(q0[j]);
        #pragma unroll
        for (int j = 0; j < 8; ++j) dot += bf2f(k1[j]) * bf2f(q1[j]);
        dot *= 0.25f;
        float s1 = __expf(clip5(dot) * adj2[e]) + rel[e];
        gsb[tid] = f2bf(s1);
        s1f[tid] = s1;
        return;
    }
    int i = (blockIdx.x - 5000) * 256 + threadIdx.x;
    if (i < EF) {
        int d = dst[i];
        int p = atomicAdd(&cnt[d], 1);
        int g = inv[i];
        unsigned w0 = (unsigned)src[i] | (g >= 0 ? 0x80000000u : 0u);
        unsigned w1 = (g >= 0) ? (unsigned)g : pk2(adj2[i], rel[i]);
        em[(size_t)d * CAP + p] = make_uint2(w0, w1);
    }
}

// ---------------------------------------------------------------------------
// e_out = e@Woute + gs@Wcomb + bcomb AND pe = e@Wpe + bpe.
// 512 threads/block (8 waves share one 32 KB Woute LDS copy) -> 4 blocks/CU
// = 32 waves/CU (100% occupancy at <=64 VGPR). Each wave owns 16 rows;
// block owns 128 rows; grid = EG/128 = 1250.
// ---------------------------------------------------------------------------
__global__ __launch_bounds__(512, 8) void mfma_eout_pe(
    const float* __restrict__ Ap, const short* __restrict__ WouteF,
    const short* __restrict__ WcombF, const float* __restrict__ bcomb,
    const short* __restrict__ gsb, const short* __restrict__ WpeF,
    const float* __restrict__ bpe, const float* __restrict__ s1f,
    float* __restrict__ out, float* __restrict__ scoreg)
{
    __shared__ short ldsW[16384];
    int tid = threadIdx.x;
    #pragma unroll
    for (int i = 0; i < 4; ++i)
        ((uint4*)ldsW)[tid + i * 512] = ((const uint4*)WouteF)[tid + i * 512];

    int lane = tid & 63;
    int w = tid >> 6;                       // 0..7
    int l15 = lane & 15, lhi = lane >> 4;
    int r = blockIdx.x * 128 + w * 16 + l15;

    bf16x8 bc8[8], bp[4];
    #pragma unroll
    for (int n = 0; n < 8; ++n)
        bc8[n] = *(const bf16x8*)(WcombF + ((size_t)(n * 64 + lane)) * 8);
    #pragma unroll
    for (int ks = 0; ks < 4; ++ks)
        bp[ks] = *(const bf16x8*)(WpeF + ((size_t)(ks * 64 + lane)) * 8);

    bf16x8 a[4], ag;
    #pragma unroll
    for (int ks = 0; ks < 4; ++ks) {
        const float* ap = Ap + (size_t)r * 128 + ks * 32 + lhi * 8;
        float4 f0 = *(const float4*)ap;
        float4 f1 = *(const float4*)(ap + 4);
        a[ks][0] = f2bf(f0.x); a[ks][1] = f2bf(f0.y);
        a[ks][2] = f2bf(f0.z); a[ks][3] = f2bf(f0.w);
        a[ks][4] = f2bf(f1.x); a[ks][5] = f2bf(f1.y);
        a[ks][6] = f2bf(f1.z); a[ks][7] = f2bf(f1.w);
    }
    if (lhi == 0) ag = *(const bf16x8*)(gsb + (size_t)r * 8);
    else {
        #pragma unroll
        for (int j = 0; j < 8; ++j) ag[j] = 0;
    }
    __syncthreads();

    #pragma unroll
    for (int n = 0; n < 8; ++n) {
        f32x4 acc = (f32x4){0.f, 0.f, 0.f, 0.f};
        #pragma unroll
        for (int ks = 0; ks < 4; ++ks) {
            bf16x8 b = *(const bf16x8*)(ldsW + ((n * 4 + ks) * 64 + lane) * 8);
            acc = __builtin_amdgcn_mfma_f32_16x16x32_bf16(b, a[ks], acc, 0, 0, 0);
        }
        acc = __builtin_amdgcn_mfma_f32_16x16x32_bf16(bc8[n], ag, acc, 0, 0, 0);
        int col0 = n * 16 + lhi * 4;
        float4 bs = *(const float4*)(bcomb + col0);
        *(float4*)(out + (size_t)r * 128 + col0) =
            make_float4(acc[0] + bs.x, acc[1] + bs.y, acc[2] + bs.z, acc[3] + bs.w);
    }

    f32x4 pacc = (f32x4){0.f, 0.f, 0.f, 0.f};
    #pragma unroll
    for (int ks = 0; ks < 4; ++ks)
        pacc = __builtin_amdgcn_mfma_f32_16x16x32_bf16(bp[ks], a[ks], pacc, 0, 0, 0);
    if (lhi < 2) {
        float4 bs = *(const float4*)(bpe + lhi * 4);
        float4 s1v = *(const float4*)(s1f + (size_t)r * 8 + lhi * 4);
        float4 sg;
        sg.x = __expf(clip5(clip5(s1v.x) + pacc[0] + bs.x));
        sg.y = __expf(clip5(clip5(s1v.y) + pacc[1] + bs.y));
        sg.z = __expf(clip5(clip5(s1v.z) + pacc[2] + bs.z));
        sg.w = __expf(clip5(clip5(s1v.w) + pacc[3] + bs.w));
        *(float4*)(scoreg + (size_t)r * 8 + lhi * 4) = sg;
    }
}

// ---------------------------------------------------------------------------
// Aggregation over fixed-capacity buckets. Wave per node; end = cnt[wid].
// ---------------------------------------------------------------------------
__global__ __launch_bounds__(256) void csr_aggregate_f8(
    const unsigned* __restrict__ Qb2, const unsigned char* __restrict__ K8,
    const unsigned char* __restrict__ V8, const uint2* __restrict__ em,
    const float* __restrict__ scoreg, const int* __restrict__ cnt,
    unsigned* __restrict__ wVn)
{
    int lane = threadIdx.x & 63;
    int wid = (blockIdx.x << 2) | (threadIdx.x >> 6);
    if (wid >= NN) return;
    int deg = cnt[wid];
    const uint2* eb = em + (size_t)wid * CAP;
    int hh = lane >> 3;
    unsigned koff = (unsigned)(lane << 1);

    unsigned qu = Qb2[(unsigned)wid * 64 + lane];
    float qx = blo(qu), qy = bhi(qu);

    float accx = 0.f, accy = 0.f, zacc = 0.f;

#define EB(KW, VW, M)                                                      \
    {                                                                      \
        f32x2 kf = __builtin_amdgcn_cvt_pk_f32_fp8((int)(KW), false);      \
        f32x2 vf = __builtin_amdgcn_cvt_pk_f32_fp8((int)(VW), false);      \
        float px = qx * kf[0] + qy * kf[1];                                \
        px += __shfl_xor(px, 1);                                           \
        px += __shfl_xor(px, 2);                                           \
        px += __shfl_xor(px, 4);                                           \
        bool isg = (int)(M).x < 0;                                         \
        float a2 = blo((M).y), rl = bhi((M).y);                            \
        float t = __expf(clip5(px * 0.25f) * a2) + rl;                     \
        float sc = __expf(clip5(t));                                       \
        unsigned gi = isg ? (M).y : 0u;                                    \
        float sg = scoreg[(size_t)gi * 8 + hh];                            \
        sc = isg ? sg : sc;                                                \
        accx += vf[0] * sc;                                                \
        accy += vf[1] * sc;                                                \
        zacc += sc;                                                        \
    }

    int p = 0;
    for (; p + 4 <= deg; p += 4) {
        uint2 m0 = eb[p],     m1 = eb[p + 1];
        uint2 m2 = eb[p + 2], m3 = eb[p + 3];
        unsigned s0 = m0.x & 0x7FFFFFFFu, s1 = m1.x & 0x7FFFFFFFu;
        unsigned s2 = m2.x & 0x7FFFFFFFu, s3 = m3.x & 0x7FFFFFFFu;
        unsigned short kw0 = *(const unsigned short*)(K8 + ((s0 << 7) | koff));
        unsigned short kw1 = *(const unsigned short*)(K8 + ((s1 << 7) | koff));
        unsigned short kw2 = *(const unsigned short*)(K8 + ((s2 << 7) | koff));
        unsigned short kw3 = *(const unsigned short*)(K8 + ((s3 << 7) | koff));
        unsigned short vw0 = *(const unsigned short*)(V8 + ((s0 << 7) | koff));
        unsigned short vw1 = *(const unsigned short*)(V8 + ((s1 << 7) | koff));
        unsigned short vw2 = *(const unsigned short*)(V8 + ((s2 << 7) | koff));
        unsigned short vw3 = *(const unsigned short*)(V8 + ((s3 << 7) | koff));
        EB(kw0, vw0, m0)
        EB(kw1, vw1, m1)
        EB(kw2, vw2, m2)
        EB(kw3, vw3, m3)
    }
    for (; p < deg; ++p) {
        uint2 m = eb[p];
        unsigned s = m.x & 0x7FFFFFFFu;
        unsigned short kw = *(const unsigned short*)(K8 + ((s << 7) | koff));
        unsigned short vw = *(const unsigned short*)(V8 + ((s << 7) | koff));
        EB(kw, vw, m)
    }
#undef EB

    float rz = 1.f / (zacc + 1e-6f);
    unsigned lo = (unsigned short)f2bf(accx * rz);
    unsigned hi = (unsigned short)f2bf(accy * rz);
    wVn[(unsigned)wid * 64 + lane] = lo | (hi << 16);
}

// ---------------------------------------------------------------------------
// h_out GEMM: B fragments in registers, grid-stride over row tiles.
// ---------------------------------------------------------------------------
__global__ __launch_bounds__(256, 2) void mfma_gemm_abf16(
    const short* __restrict__ Ap, const short* __restrict__ BF,
    const float* __restrict__ bias, float* __restrict__ out, int M)
{
    int lane = threadIdx.x & 63;
    int w = threadIdx.x >> 6;
    int l15 = lane & 15, lhi = lane >> 4;

    bf16x8 bf[8][4];
    #pragma unroll
    for (int n = 0; n < 8; ++n)
        #pragma unroll
        for (int ks = 0; ks < 4; ++ks)
            bf[n][ks] = *(const bf16x8*)(BF + ((size_t)((n * 4 + ks) * 64 + lane)) * 8);

    int ntile = (M + 63) / 64;
    for (int t = blockIdx.x; t < ntile; t += gridDim.x) {
        int r = t * 64 + w * 16 + l15;
        bool ok = r < M;
        bf16x8 a[4];
        #pragma unroll
        for (int ks = 0; ks < 4; ++ks) {
            if (ok) a[ks] = *(const bf16x8*)(Ap + (size_t)r * 128 + ks * 32 + lhi * 8);
            else {
                #pragma unroll
                for (int j = 0; j < 8; ++j) a[ks][j] = 0;
            }
        }
        #pragma unroll
        for (int n = 0; n < 8; ++n) {
            f32x4 acc = (f32x4){0.f, 0.f, 0.f, 0.f};
            #pragma unroll
            for (int ks = 0; ks < 4; ++ks)
                acc = __builtin_amdgcn_mfma_f32_16x16x32_bf16(bf[n][ks], a[ks], acc, 0, 0, 0);
            if (!ok) continue;
            int col0 = n * 16 + lhi * 4;
            float4 bs = *(const float4*)(bias + col0);
            *(float4*)(out + (size_t)r * 128 + col0) =
                make_float4(acc[0] + bs.x, acc[1] + bs.y, acc[2] + bs.z, acc[3] + bs.w);
        }
    }
}

extern "C" void kernel_launch(void* const* d_in, const int* in_sizes, int n_in,
                              void* d_out, int out_size, void* d_ws, size_t ws_size,
                              hipStream_t stream)
{
    const float* h    = (const float*)d_in[0];
    const float* e    = (const float*)d_in[1];
    const float* adj2 = (const float*)d_in[2];
    const float* rel  = (const float*)d_in[3];
    const int*   src  = (const int*)d_in[4];
    const int*   dst  = (const int*)d_in[5];
    const int*   emap = (const int*)d_in[6];
    const float* Wq = (const float*)d_in[7];   const float* bq = (const float*)d_in[8];
    const float* Wk = (const float*)d_in[9];   const float* bk = (const float*)d_in[10];
    const float* Wv = (const float*)d_in[11];  const float* bv = (const float*)d_in[12];
    const float* Wpe = (const float*)d_in[13]; const float* bpe = (const float*)d_in[14];
    const float* Wap = (const float*)d_in[15]; const float* bap = (const float*)d_in[16];
    const float* Wout = (const float*)d_in[17]; const float* bout = (const float*)d_in[18];
    const float* Woute = (const float*)d_in[19]; const float* boute = (const float*)d_in[20];

    float* ws = (float*)d_ws;
    float*    scoreg = ws;                          // 1,280,000
    float*    s1f    = ws + 1280000;                // 1,280,000
    unsigned* wVn    = (unsigned*)(ws + 2560000);   // 1,280,000
    short*    Qb     = (short*)(ws + 3840000);      // 2,560,000 bf16
    short*    Kb     = (short*)(ws + 5120000);
    short*    gsb    = (short*)(ws + 6400000);      // 1,280,000 bf16
    unsigned char* K8 = (unsigned char*)(ws + 7040000);   // 2,560,000 B
    unsigned char* V8 = (unsigned char*)(ws + 7680000);   // 2,560,000 B
    short*    WqF    = (short*)(ws + 8320000);      // 16384 shorts each
    short*    WkF    = (short*)(ws + 8328192);
    short*    WvF    = (short*)(ws + 8336384);
    short*    WoutF  = (short*)(ws + 8344576);
    short*    WouteF = (short*)(ws + 8352768);
    short*    WcombF = (short*)(ws + 8360960);      // 4096 shorts
    short*    WpeF   = (short*)(ws + 8363008);      // 2048 shorts
    float*    bcomb  = ws + 8364032;                // 128
    uint2*    em     = (uint2*)(ws + 8364160);      // NN*CAP = 2,560,000 uint2
    int*      inv    = (int*)(ws + 13484160);       // 640,000
    int*      cnt    = (int*)(ws + 14124160);       // 20,000
    float* h_out = (float*)d_out;
    float* e_out = (float*)d_out + 2560000;

    // L1: fused prep (init cnt/inv + weight transforms)
    prep_kernel<<<2542, 256, 0, stream>>>(
        cnt, inv, Wq, Wk, Wv, Wout, Woute, WqF, WkF, WvF, WoutF, WouteF,
        Wpe, WpeF, Wap, bap, Woute, boute, WcombF, bcomb);

    // L2: inv || qkv
    iq_kernel<<<881, 256, 0, stream>>>(
        emap, inv, h, WqF, WkF, WvF, bq, bk, bv, Qb, Kb, K8, V8);

    // L3: score_g || bucket-scatter
    ss_kernel<<<7500, 256, 0, stream>>>(
        Qb, Kb, src, dst, adj2, rel, emap, gsb, s1f, inv, cnt, em);

    // L4: eout_pe (512 threads, 8 waves share LDS, full occupancy)
    mfma_eout_pe<<<1250, 512, 0, stream>>>(e, WouteF, WcombF, bcomb, gsb,
                                           WpeF, bpe, s1f, e_out, scoreg);

    // L5: aggregate
    csr_aggregate_f8<<<5000, 256, 0, stream>>>(
        (const unsigned*)Qb, K8, V8, em, scoreg, cnt, wVn);

    // L6: h_out
    mfma_gemm_abf16<<<256, 256, 0, stream>>>((const short*)wVn, WoutF, bout, h_out, NN);
}

// Round 25
// 194.529 us; speedup vs baseline: 1.2583x; 1.2583x over previous
//
#include <hip/hip_runtime.h>
#include <hip/hip_bf16.h>

#define NN 20000
#define EF 640000
#define EG 160000
#define CAP 128   // per-node edge bucket capacity (deg ~ Poisson(32))

typedef __attribute__((ext_vector_type(8))) short bf16x8;
typedef __attribute__((ext_vector_type(4))) float f32x4;
typedef __attribute__((ext_vector_type(2))) float f32x2;

__device__ inline short f2bf(float f) {
    union { float f; unsigned u; } x; x.f = f;
    unsigned r = x.u + 0x7FFF + ((x.u >> 16) & 1);   // RNE
    return (short)(r >> 16);
}
__device__ inline float bf2f(short s) {
    union { float f; unsigned u; } x;
    x.u = ((unsigned)(unsigned short)s) << 16;
    return x.f;
}
__device__ inline float blo(unsigned u) {
    union { float f; unsigned u; } c; c.u = u << 16; return c.f;
}
__device__ inline float bhi(unsigned u) {
    union { float f; unsigned u; } c; c.u = u & 0xFFFF0000u; return c.f;
}
__device__ inline unsigned pk2(float a, float b) {
    return (unsigned)(unsigned short)f2bf(a) | ((unsigned)(unsigned short)f2bf(b) << 16);
}
__device__ inline float clip5(float v) { return fminf(fmaxf(v, -5.f), 5.f); }

// ---------------------------------------------------------------------------
// prep_kernel: fused {init cnt/inv} + {5x weight->frag-major} + WpeF + Wcomb
// ---------------------------------------------------------------------------
__global__ __launch_bounds__(256) void prep_kernel(
    int* __restrict__ cnt, int* __restrict__ inv,
    const float* __restrict__ W0, const float* __restrict__ W1,
    const float* __restrict__ W2, const float* __restrict__ W3,
    const float* __restrict__ W4, short* __restrict__ B0,
    short* __restrict__ B1, short* __restrict__ B2,
    short* __restrict__ B3, short* __restrict__ B4,
    const float* __restrict__ Wpe, short* __restrict__ WpeF,
    const float* __restrict__ Wap, const float* __restrict__ bap,
    const float* __restrict__ Woute, const float* __restrict__ boute,
    short* __restrict__ WcombF, float* __restrict__ bcomb)
{
    int b = blockIdx.x;
    int tid = threadIdx.x;
    if (b < 2500) {
        int i = b * 256 + tid;
        if (i < NN) cnt[i] = 0;
        if (i < EF) inv[i] = -1;
    } else if (b < 2540) {
        int u = b - 2500;
        int mat = u >> 3, blk = u & 7;
        const float* W; short* B;
        switch (mat) {
            case 0: W = W0; B = B0; break;
            case 1: W = W1; B = B1; break;
            case 2: W = W2; B = B2; break;
            case 3: W = W3; B = B3; break;
            default: W = W4; B = B4; break;
        }
        int i = blk * 256 + tid;
        int f = i >> 6, lane = i & 63;
        int n = f >> 2, ks = f & 3;
        int col = n * 16 + (lane & 15);
        int k0 = ks * 32 + (lane >> 4) * 8;
        #pragma unroll
        for (int j = 0; j < 8; ++j)
            B[(size_t)i * 8 + j] = f2bf(W[(size_t)(k0 + j) * 128 + col]);
    } else if (b == 2540) {
        int i = tid;
        int lane = i & 63;
        int ks = i >> 6;
        int l15 = lane & 15, lhi = lane >> 4;
        #pragma unroll
        for (int j = 0; j < 8; ++j) {
            int k = ks * 32 + lhi * 8 + j;
            WpeF[(size_t)i * 8 + j] = (l15 < 8) ? f2bf(Wpe[k * 8 + l15]) : 0;
        }
    } else {
        int j = tid;
        if (j < 128) {
            #pragma unroll
            for (int t = 0; t < 32; ++t) WcombF[j * 32 + t] = 0;
        }
        __syncthreads();
        if (j < 128) {
            float bc = boute[j];
            for (int k = 0; k < 128; ++k) bc += bap[k] * Woute[k * 128 + j];
            bcomb[j] = bc;
            int n = j >> 4, l15 = j & 15;
            #pragma unroll
            for (int i = 0; i < 8; ++i) {
                float s = 0.f;
                for (int k = 0; k < 128; ++k) s += Wap[i * 128 + k] * Woute[k * 128 + j];
                WcombF[((size_t)n * 64 + l15) * 8 + i] = f2bf(s);
            }
        }
    }
}

// ---------------------------------------------------------------------------
// L2: inv [0,625) || qkv_fused [625,881)
// ---------------------------------------------------------------------------
__global__ __launch_bounds__(256, 2) void iq_kernel(
    const int* __restrict__ emap, int* __restrict__ inv,
    const float* __restrict__ h,
    const short* __restrict__ WqF, const short* __restrict__ WkF,
    const short* __restrict__ WvF,
    const float* __restrict__ bq, const float* __restrict__ bk,
    const float* __restrict__ bv,
    short* __restrict__ Qb, short* __restrict__ Kb,
    unsigned char* __restrict__ K8, unsigned char* __restrict__ V8)
{
    if (blockIdx.x < 625) {
        int i = blockIdx.x * 256 + threadIdx.x;
        if (i < EG) inv[emap[i]] = i;
        return;
    }
    int bq0 = blockIdx.x - 625;   // 0..255
    int lane = threadIdx.x & 63;
    int w = threadIdx.x >> 6;
    int l15 = lane & 15, lhi = lane >> 4;

    #pragma unroll
    for (int sel = 0; sel < 3; ++sel) {
        const short* BF  = sel == 0 ? WqF : sel == 1 ? WkF : WvF;
        const float* bias = sel == 0 ? bq : sel == 1 ? bk : bv;
        bf16x8 bf[8][4];
        #pragma unroll
        for (int n = 0; n < 8; ++n)
            #pragma unroll
            for (int ks = 0; ks < 4; ++ks)
                bf[n][ks] = *(const bf16x8*)(BF + ((size_t)((n * 4 + ks) * 64 + lane)) * 8);

        for (int t = bq0; t < 313; t += 256) {
            int r = t * 64 + w * 16 + l15;
            bool ok = r < NN;
            bf16x8 a[4];
            #pragma unroll
            for (int ks = 0; ks < 4; ++ks) {
                if (ok) {
                    const float* ap = h + (size_t)r * 128 + ks * 32 + lhi * 8;
                    float4 f0 = *(const float4*)ap;
                    float4 f1 = *(const float4*)(ap + 4);
                    a[ks][0] = f2bf(f0.x); a[ks][1] = f2bf(f0.y);
                    a[ks][2] = f2bf(f0.z); a[ks][3] = f2bf(f0.w);
                    a[ks][4] = f2bf(f1.x); a[ks][5] = f2bf(f1.y);
                    a[ks][6] = f2bf(f1.z); a[ks][7] = f2bf(f1.w);
                } else {
                    #pragma unroll
                    for (int j = 0; j < 8; ++j) a[ks][j] = 0;
                }
            }
            #pragma unroll
            for (int n = 0; n < 8; ++n) {
                f32x4 acc = (f32x4){0.f, 0.f, 0.f, 0.f};
                #pragma unroll
                for (int ks = 0; ks < 4; ++ks)
                    acc = __builtin_amdgcn_mfma_f32_16x16x32_bf16(bf[n][ks], a[ks], acc, 0, 0, 0);
                if (!ok) continue;
                int col0 = n * 16 + lhi * 4;
                float4 bs = *(const float4*)(bias + col0);
                float g0 = acc[0] + bs.x, g1 = acc[1] + bs.y;
                float g2 = acc[2] + bs.z, g3 = acc[3] + bs.w;
                if (sel == 0) {
                    *(uint2*)(Qb + (size_t)r * 128 + col0) =
                        make_uint2(pk2(g0, g1), pk2(g2, g3));
                } else if (sel == 1) {
                    *(uint2*)(Kb + (size_t)r * 128 + col0) =
                        make_uint2(pk2(g0, g1), pk2(g2, g3));
                    int w8 = __builtin_amdgcn_cvt_pk_fp8_f32(g0, g1, 0, false);
                    w8 = __builtin_amdgcn_cvt_pk_fp8_f32(g2, g3, w8, true);
                    *(unsigned*)(K8 + (size_t)r * 128 + col0) = (unsigned)w8;
                } else {
                    int w8 = __builtin_amdgcn_cvt_pk_fp8_f32(g0, g1, 0, false);
                    w8 = __builtin_amdgcn_cvt_pk_fp8_f32(g2, g3, w8, true);
                    *(unsigned*)(V8 + (size_t)r * 128 + col0) = (unsigned)w8;
                }
            }
        }
    }
}

// ---------------------------------------------------------------------------
// L3: score_g [0,5000) || bucket-scatter [5000,7500)
// ---------------------------------------------------------------------------
__global__ __launch_bounds__(256) void ss_kernel(
    const short* __restrict__ Qb, const short* __restrict__ Kb,
    const int* __restrict__ src, const int* __restrict__ dst,
    const float* __restrict__ adj2, const float* __restrict__ rel,
    const int* __restrict__ emap,
    short* __restrict__ gsb, float* __restrict__ s1f,
    const int* __restrict__ inv, int* __restrict__ cnt,
    uint2* __restrict__ em)
{
    if (blockIdx.x < 5000) {
        int tid = blockIdx.x * 256 + threadIdx.x;
        if (tid >= EG * 8) return;
        int i = tid >> 3, hh = tid & 7;
        int e = emap[i];
        int s = src[e], d = dst[e];
        const bf16x8* Kp = (const bf16x8*)(Kb + (size_t)s * 128 + hh * 16);
        const bf16x8* Qp = (const bf16x8*)(Qb + (size_t)d * 128 + hh * 16);
        bf16x8 k0 = Kp[0], k1 = Kp[1];
        bf16x8 q0 = Qp[0], q1 = Qp[1];
        float dot = 0.f;
        #pragma unroll
        for (int j = 0; j < 8; ++j) dot += bf2f(k0[j]) * bf2f(q0[j]);
        #pragma unroll
        for (int j = 0; j < 8; ++j) dot += bf2f(k1[j]) * bf2f(q1[j]);
        dot *= 0.25f;
        float s1 = __expf(clip5(dot) * adj2[e]) + rel[e];
        gsb[tid] = f2bf(s1);
        s1f[tid] = s1;
        return;
    }
    int i = (blockIdx.x - 5000) * 256 + threadIdx.x;
    if (i < EF) {
        int d = dst[i];
        int p = atomicAdd(&cnt[d], 1);
        int g = inv[i];
        unsigned w0 = (unsigned)src[i] | (g >= 0 ? 0x80000000u : 0u);
        unsigned w1 = (g >= 0) ? (unsigned)g : pk2(adj2[i], rel[i]);
        em[(size_t)d * CAP + p] = make_uint2(w0, w1);
    }
}

// ---------------------------------------------------------------------------
// e_out = e@Woute + gs@Wcomb + bcomb AND pe = e@Wpe + bpe.
// Woute frags in LDS; Wcomb/Wpe frags in registers. (round-23 measured best)
// ---------------------------------------------------------------------------
__global__ __launch_bounds__(256, 3) void mfma_eout_pe(
    const float* __restrict__ Ap, const short* __restrict__ WouteF,
    const short* __restrict__ WcombF, const float* __restrict__ bcomb,
    const short* __restrict__ gsb, const short* __restrict__ WpeF,
    const float* __restrict__ bpe, const float* __restrict__ s1f,
    float* __restrict__ out, float* __restrict__ scoreg)
{
    __shared__ short ldsW[16384];
    int tid = threadIdx.x;
    #pragma unroll
    for (int i = 0; i < 8; ++i)
        ((uint4*)ldsW)[tid + i * 256] = ((const uint4*)WouteF)[tid + i * 256];

    int lane = tid & 63;
    int w = tid >> 6;
    int l15 = lane & 15, lhi = lane >> 4;
    int r = blockIdx.x * 64 + w * 16 + l15;

    bf16x8 bc8[8], bp[4];
    #pragma unroll
    for (int n = 0; n < 8; ++n)
        bc8[n] = *(const bf16x8*)(WcombF + ((size_t)(n * 64 + lane)) * 8);
    #pragma unroll
    for (int ks = 0; ks < 4; ++ks)
        bp[ks] = *(const bf16x8*)(WpeF + ((size_t)(ks * 64 + lane)) * 8);

    bf16x8 a[4], ag;
    #pragma unroll
    for (int ks = 0; ks < 4; ++ks) {
        const float* ap = Ap + (size_t)r * 128 + ks * 32 + lhi * 8;
        float4 f0 = *(const float4*)ap;
        float4 f1 = *(const float4*)(ap + 4);
        a[ks][0] = f2bf(f0.x); a[ks][1] = f2bf(f0.y);
        a[ks][2] = f2bf(f0.z); a[ks][3] = f2bf(f0.w);
        a[ks][4] = f2bf(f1.x); a[ks][5] = f2bf(f1.y);
        a[ks][6] = f2bf(f1.z); a[ks][7] = f2bf(f1.w);
    }
    if (lhi == 0) ag = *(const bf16x8*)(gsb + (size_t)r * 8);
    else {
        #pragma unroll
        for (int j = 0; j < 8; ++j) ag[j] = 0;
    }
    __syncthreads();

    #pragma unroll
    for (int n = 0; n < 8; ++n) {
        f32x4 acc = (f32x4){0.f, 0.f, 0.f, 0.f};
        #pragma unroll
        for (int ks = 0; ks < 4; ++ks) {
            bf16x8 b = *(const bf16x8*)(ldsW + ((n * 4 + ks) * 64 + lane) * 8);
            acc = __builtin_amdgcn_mfma_f32_16x16x32_bf16(b, a[ks], acc, 0, 0, 0);
        }
        acc = __builtin_amdgcn_mfma_f32_16x16x32_bf16(bc8[n], ag, acc, 0, 0, 0);
        int col0 = n * 16 + lhi * 4;
        float4 bs = *(const float4*)(bcomb + col0);
        *(float4*)(out + (size_t)r * 128 + col0) =
            make_float4(acc[0] + bs.x, acc[1] + bs.y, acc[2] + bs.z, acc[3] + bs.w);
    }

    f32x4 pacc = (f32x4){0.f, 0.f, 0.f, 0.f};
    #pragma unroll
    for (int ks = 0; ks < 4; ++ks)
        pacc = __builtin_amdgcn_mfma_f32_16x16x32_bf16(bp[ks], a[ks], pacc, 0, 0, 0);
    if (lhi < 2) {
        float4 bs = *(const float4*)(bpe + lhi * 4);
        float4 s1v = *(const float4*)(s1f + (size_t)r * 8 + lhi * 4);
        float4 sg;
        sg.x = __expf(clip5(clip5(s1v.x) + pacc[0] + bs.x));
        sg.y = __expf(clip5(clip5(s1v.y) + pacc[1] + bs.y));
        sg.z = __expf(clip5(clip5(s1v.z) + pacc[2] + bs.z));
        sg.w = __expf(clip5(clip5(s1v.w) + pacc[3] + bs.w));
        *(float4*)(scoreg + (size_t)r * 8 + lhi * 4) = sg;
    }
}

// ---------------------------------------------------------------------------
// Aggregation over fixed-capacity buckets. Wave per node; end = cnt[wid].
// ---------------------------------------------------------------------------
__global__ __launch_bounds__(256) void csr_aggregate_f8(
    const unsigned* __restrict__ Qb2, const unsigned char* __restrict__ K8,
    const unsigned char* __restrict__ V8, const uint2* __restrict__ em,
    const float* __restrict__ scoreg, const int* __restrict__ cnt,
    unsigned* __restrict__ wVn)
{
    int lane = threadIdx.x & 63;
    int wid = (blockIdx.x << 2) | (threadIdx.x >> 6);
    if (wid >= NN) return;
    int deg = cnt[wid];
    const uint2* eb = em + (size_t)wid * CAP;
    int hh = lane >> 3;
    unsigned koff = (unsigned)(lane << 1);

    unsigned qu = Qb2[(unsigned)wid * 64 + lane];
    float qx = blo(qu), qy = bhi(qu);

    float accx = 0.f, accy = 0.f, zacc = 0.f;

#define EB(KW, VW, M)                                                      \
    {                                                                      \
        f32x2 kf = __builtin_amdgcn_cvt_pk_f32_fp8((int)(KW), false);      \
        f32x2 vf = __builtin_amdgcn_cvt_pk_f32_fp8((int)(VW), false);      \
        float px = qx * kf[0] + qy * kf[1];                                \
        px += __shfl_xor(px, 1);                                           \
        px += __shfl_xor(px, 2);                                           \
        px += __shfl_xor(px, 4);                                           \
        bool isg = (int)(M).x < 0;                                         \
        float a2 = blo((M).y), rl = bhi((M).y);                            \
        float t = __expf(clip5(px * 0.25f) * a2) + rl;                     \
        float sc = __expf(clip5(t));                                       \
        unsigned gi = isg ? (M).y : 0u;                                    \
        float sg = scoreg[(size_t)gi * 8 + hh];                            \
        sc = isg ? sg : sc;                                                \
        accx += vf[0] * sc;                                                \
        accy += vf[1] * sc;                                                \
        zacc += sc;                                                        \
    }

    int p = 0;
    for (; p + 4 <= deg; p += 4) {
        uint2 m0 = eb[p],     m1 = eb[p + 1];
        uint2 m2 = eb[p + 2], m3 = eb[p + 3];
        unsigned s0 = m0.x & 0x7FFFFFFFu, s1 = m1.x & 0x7FFFFFFFu;
        unsigned s2 = m2.x & 0x7FFFFFFFu, s3 = m3.x & 0x7FFFFFFFu;
        unsigned short kw0 = *(const unsigned short*)(K8 + ((s0 << 7) | koff));
        unsigned short kw1 = *(const unsigned short*)(K8 + ((s1 << 7) | koff));
        unsigned short kw2 = *(const unsigned short*)(K8 + ((s2 << 7) | koff));
        unsigned short kw3 = *(const unsigned short*)(K8 + ((s3 << 7) | koff));
        unsigned short vw0 = *(const unsigned short*)(V8 + ((s0 << 7) | koff));
        unsigned short vw1 = *(const unsigned short*)(V8 + ((s1 << 7) | koff));
        unsigned short vw2 = *(const unsigned short*)(V8 + ((s2 << 7) | koff));
        unsigned short vw3 = *(const unsigned short*)(V8 + ((s3 << 7) | koff));
        EB(kw0, vw0, m0)
        EB(kw1, vw1, m1)
        EB(kw2, vw2, m2)
        EB(kw3, vw3, m3)
    }
    for (; p < deg; ++p) {
        uint2 m = eb[p];
        unsigned s = m.x & 0x7FFFFFFFu;
        unsigned short kw = *(const unsigned short*)(K8 + ((s << 7) | koff));
        unsigned short vw = *(const unsigned short*)(V8 + ((s << 7) | koff));
        EB(kw, vw, m)
    }
#undef EB

    float rz = 1.f / (zacc + 1e-6f);
    unsigned lo = (unsigned short)f2bf(accx * rz);
    unsigned hi = (unsigned short)f2bf(accy * rz);
    wVn[(unsigned)wid * 64 + lane] = lo | (hi << 16);
}

// ---------------------------------------------------------------------------
// h_out GEMM: B fragments in registers, grid-stride over row tiles.
// ---------------------------------------------------------------------------
__global__ __launch_bounds__(256, 2) void mfma_gemm_abf16(
    const short* __restrict__ Ap, const short* __restrict__ BF,
    const float* __restrict__ bias, float* __restrict__ out, int M)
{
    int lane = threadIdx.x & 63;
    int w = threadIdx.x >> 6;
    int l15 = lane & 15, lhi = lane >> 4;

    bf16x8 bf[8][4];
    #pragma unroll
    for (int n = 0; n < 8; ++n)
        #pragma unroll
        for (int ks = 0; ks < 4; ++ks)
            bf[n][ks] = *(const bf16x8*)(BF + ((size_t)((n * 4 + ks) * 64 + lane)) * 8);

    int ntile = (M + 63) / 64;
    for (int t = blockIdx.x; t < ntile; t += gridDim.x) {
        int r = t * 64 + w * 16 + l15;
        bool ok = r < M;
        bf16x8 a[4];
        #pragma unroll
        for (int ks = 0; ks < 4; ++ks) {
            if (ok) a[ks] = *(const bf16x8*)(Ap + (size_t)r * 128 + ks * 32 + lhi * 8);
            else {
                #pragma unroll
                for (int j = 0; j < 8; ++j) a[ks][j] = 0;
            }
        }
        #pragma unroll
        for (int n = 0; n < 8; ++n) {
            f32x4 acc = (f32x4){0.f, 0.f, 0.f, 0.f};
            #pragma unroll
            for (int ks = 0; ks < 4; ++ks)
                acc = __builtin_amdgcn_mfma_f32_16x16x32_bf16(bf[n][ks], a[ks], acc, 0, 0, 0);
            if (!ok) continue;
            int col0 = n * 16 + lhi * 4;
            float4 bs = *(const float4*)(bias + col0);
            *(float4*)(out + (size_t)r * 128 + col0) =
                make_float4(acc[0] + bs.x, acc[1] + bs.y, acc[2] + bs.z, acc[3] + bs.w);
        }
    }
}

extern "C" void kernel_launch(void* const* d_in, const int* in_sizes, int n_in,
                              void* d_out, int out_size, void* d_ws, size_t ws_size,
                              hipStream_t stream)
{
    const float* h    = (const float*)d_in[0];
    const float* e    = (const float*)d_in[1];
    const float* adj2 = (const float*)d_in[2];
    const float* rel  = (const float*)d_in[3];
    const int*   src  = (const int*)d_in[4];
    const int*   dst  = (const int*)d_in[5];
    const int*   emap = (const int*)d_in[6];
    const float* Wq = (const float*)d_in[7];   const float* bq = (const float*)d_in[8];
    const float* Wk = (const float*)d_in[9];   const float* bk = (const float*)d_in[10];
    const float* Wv = (const float*)d_in[11];  const float* bv = (const float*)d_in[12];
    const float* Wpe = (const float*)d_in[13]; const float* bpe = (const float*)d_in[14];
    const float* Wap = (const float*)d_in[15]; const float* bap = (const float*)d_in[16];
    const float* Wout = (const float*)d_in[17]; const float* bout = (const float*)d_in[18];
    const float* Woute = (const float*)d_in[19]; const float* boute = (const float*)d_in[20];

    float* ws = (float*)d_ws;
    float*    scoreg = ws;                          // 1,280,000
    float*    s1f    = ws + 1280000;                // 1,280,000
    unsigned* wVn    = (unsigned*)(ws + 2560000);   // 1,280,000
    short*    Qb     = (short*)(ws + 3840000);      // 2,560,000 bf16
    short*    Kb     = (short*)(ws + 5120000);
    short*    gsb    = (short*)(ws + 6400000);      // 1,280,000 bf16
    unsigned char* K8 = (unsigned char*)(ws + 7040000);   // 2,560,000 B
    unsigned char* V8 = (unsigned char*)(ws + 7680000);   // 2,560,000 B
    short*    WqF    = (short*)(ws + 8320000);      // 16384 shorts each
    short*    WkF    = (short*)(ws + 8328192);
    short*    WvF    = (short*)(ws + 8336384);
    short*    WoutF  = (short*)(ws + 8344576);
    short*    WouteF = (short*)(ws + 8352768);
    short*    WcombF = (short*)(ws + 8360960);      // 4096 shorts
    short*    WpeF   = (short*)(ws + 8363008);      // 2048 shorts
    float*    bcomb  = ws + 8364032;                // 128
    uint2*    em     = (uint2*)(ws + 8364160);      // NN*CAP = 2,560,000 uint2
    int*      inv    = (int*)(ws + 13484160);       // 640,000
    int*      cnt    = (int*)(ws + 14124160);       // 20,000
    float* h_out = (float*)d_out;
    float* e_out = (float*)d_out + 2560000;

    // L1: fused prep (init cnt/inv + weight transforms)
    prep_kernel<<<2542, 256, 0, stream>>>(
        cnt, inv, Wq, Wk, Wv, Wout, Woute, WqF, WkF, WvF, WoutF, WouteF,
        Wpe, WpeF, Wap, bap, Woute, boute, WcombF, bcomb);

    // L2: inv || qkv
    iq_kernel<<<881, 256, 0, stream>>>(
        emap, inv, h, WqF, WkF, WvF, bq, bk, bv, Qb, Kb, K8, V8);

    // L3: score_g || bucket-scatter
    ss_kernel<<<7500, 256, 0, stream>>>(
        Qb, Kb, src, dst, adj2, rel, emap, gsb, s1f, inv, cnt, em);

    // L4: eout_pe (round-23 measured-best form)
    mfma_eout_pe<<<2500, 256, 0, stream>>>(e, WouteF, WcombF, bcomb, gsb,
                                           WpeF, bpe, s1f, e_out, scoreg);

    // L5: aggregate
    csr_aggregate_f8<<<5000, 256, 0, stream>>>(
        (const unsigned*)Qb, K8, V8, em, scoreg, cnt, wVn);

    // L6: h_out
    mfma_gemm_abf16<<<256, 256, 0, stream>>>((const short*)wVn, WoutF, bout, h_out, NN);
}